// Round 3
// baseline (11625.758 us; speedup 1.0000x reference)
//
#include <hip/hip_runtime.h>

// ---------------- types / helpers ----------------
typedef _Float16 f16;
typedef _Float16 f16x8 __attribute__((ext_vector_type(8)));
typedef float    f32x4 __attribute__((ext_vector_type(4)));

#define GLOAD16(gptr, lptr)                                                    \
  __builtin_amdgcn_global_load_lds(                                            \
      (const __attribute__((address_space(1))) void*)(gptr),                   \
      (__attribute__((address_space(3))) void*)(lptr), 16, 0, 0)

static __device__ __forceinline__ float sigm(float x) {
  return 1.f / (1.f + __expf(-x));
}
static __device__ __forceinline__ float tanh_f(float x) {
  return 2.f / (1.f + __expf(-2.f * x)) - 1.f;   // graceful at +-inf
}

// problem constants
#define TSEQ 512
#define BATCH 64
#define HID 512
#define INW 168
#define PREW 168
#define CHUNK 128   // time steps per pre-GEMM / lstm chunk (TSEQ/CHUNK = 4)

// ---------------- tiny kernels ----------------
__global__ void k_zero_bars(int* bars) {
  if (threadIdx.x < 16) bars[threadIdx.x] = 0;
}

__global__ void k_sent(float* out, float v) { out[0] = v; }

// x [B][T][168] fp32 -> A-panels xf[t][kh<24][m<64][e<8] f16, K padded 168->192 with zeros
// FIX(r3): decompose cid so the layout is [t][kh][m][8] (was [t][m][kh][8] — scrambled GEMM A reads)
__global__ void k_conv_x(const float* __restrict__ x, f16* __restrict__ xf) {
  int cid = blockIdx.x * 256 + threadIdx.x;          // 512*24*64
  int m  = cid & 63;
  int kh = (cid >> 6) % 24;
  int t  = cid / (64 * 24);
  f16x8 o;
  if (kh < 21) {
    const float* p = x + ((size_t)m * TSEQ + t) * INW + kh * 8;
#pragma unroll
    for (int i = 0; i < 8; i++) o[i] = (f16)p[i];
  } else {
#pragma unroll
    for (int i = 0; i < 8; i++) o[i] = (f16)0.f;
  }
  *(f16x8*)(xf + (size_t)cid * 8) = o;
}

// W fp32 [Nrows][K] -> B-panels P[nb][kh<KHp][n'<64][e<8] f16, zero-padded in n and k
__global__ void k_conv_w(const float* __restrict__ W, f16* __restrict__ P,
                         int Nrows, int K, int KHp, int total) {
  int cid = blockIdx.x * 256 + threadIdx.x;
  if (cid >= total) return;
  int n_ = cid & 63;
  int kh = (cid >> 6) % KHp;
  int nb = cid / (64 * KHp);
  int row = nb * 64 + n_;
  f16x8 o;
#pragma unroll
  for (int i = 0; i < 8; i++) {
    int k = kh * 8 + i;
    float v = (row < Nrows && k < K) ? W[(size_t)row * K + k] : 0.f;
    o[i] = (f16)v;
  }
  *(f16x8*)(P + (size_t)cid * 8) = o;
}

// ---------------- GEMM: pre[d][tl<128][m<64][2048] f16 = Apanels @ Bpanels^T + bias --------
// A-panels: [t][KH][64][8], global rows t*64+m ; B-panels: [nb (+32 per dir)][KH][64][8]
// covers time slots tl = 0..127, global t = tBase(d) + tl
__global__ __launch_bounds__(256) void k_gemm_pre(
    const f16* __restrict__ Ap, const f16* __restrict__ Bp,
    const float* __restrict__ bias, f16* __restrict__ Cpre, int KH,
    int tb0, int tb1) {
  __shared__ f16 Alds[4096];
  __shared__ f16 Blds[4096];
  __shared__ f16 Clds[128 * 128];

  int tid = threadIdx.x;
  int w = tid >> 6, lane = tid & 63, quad = lane >> 4, lc = lane & 15;
  int mh = w & 1, nh = w >> 1;
  int d = blockIdx.z;
  int tBase = d ? tb1 : tb0;
  size_t rbA0 = (size_t)tBase + blockIdx.y * 2;      // global t of first row-block
  size_t nb0 = (size_t)d * 32 + blockIdx.x * 2;
  int kIters = KH >> 2;

  f32x4 acc[4][4];
#pragma unroll
  for (int a = 0; a < 4; a++)
#pragma unroll
    for (int b = 0; b < 4; b++) acc[a][b] = (f32x4){0.f, 0.f, 0.f, 0.f};

  int wv = tid >> 6;
  for (int kk = 0; kk < kIters; kk++) {
    __syncthreads();
    GLOAD16(Ap + ((rbA0 + 0) * KH + kk * 4) * 512 + tid * 8, &Alds[0    + wv * 512]);
    GLOAD16(Ap + ((rbA0 + 1) * KH + kk * 4) * 512 + tid * 8, &Alds[2048 + wv * 512]);
    GLOAD16(Bp + ((nb0 + 0) * KH + kk * 4) * 512 + tid * 8, &Blds[0    + wv * 512]);
    GLOAD16(Bp + ((nb0 + 1) * KH + kk * 4) * 512 + tid * 8, &Blds[2048 + wv * 512]);
    __syncthreads();

    f16x8 af[4], bf[4];
#pragma unroll
    for (int i = 0; i < 4; i++)
      af[i] = *(const f16x8*)&Alds[(((mh * 4 + quad) * 64) + i * 16 + lc) * 8];
#pragma unroll
    for (int i = 0; i < 4; i++)
      bf[i] = *(const f16x8*)&Blds[(((nh * 4 + quad) * 64) + i * 16 + lc) * 8];
#pragma unroll
    for (int mt = 0; mt < 4; mt++)
#pragma unroll
      for (int nt = 0; nt < 4; nt++)
        acc[mt][nt] = __builtin_amdgcn_mfma_f32_16x16x32_f16(af[mt], bf[nt],
                                                             acc[mt][nt], 0, 0, 0);
  }
  __syncthreads();

  // bias + f16 convert into Clds [row][col]
#pragma unroll
  for (int nt = 0; nt < 4; nt++) {
    int col = nh * 64 + nt * 16 + lc;
    float bv = bias[d * 2048 + blockIdx.x * 128 + col];
#pragma unroll
    for (int mt = 0; mt < 4; mt++) {
      int row0 = mh * 64 + mt * 16 + quad * 4;
#pragma unroll
      for (int r = 0; r < 4; r++)
        Clds[(row0 + r) * 128 + col] = (f16)(acc[mt][nt][r] + bv);
    }
  }
  __syncthreads();

  // coalesced write-out into chunked pre[d][tl][m][2048]
  int row = tid >> 1, half = tid & 1;
  size_t rg = (size_t)blockIdx.y * 128 + row;        // tl*64 + m
  f16* dst = Cpre + ((size_t)d * 8192 + rg) * 2048 + blockIdx.x * 128 + half * 64;
  const f16* srcl = &Clds[row * 128 + half * 64];
#pragma unroll
  for (int i = 0; i < 8; i++) *(f16x8*)(dst + i * 8) = *(const f16x8*)(srcl + i * 8);
}

// ---------------- GEMM out: out[m][t][168] fp32 = h2panels @ Woutpanels^T + bout ----------------
__global__ __launch_bounds__(256) void k_gemm_out(
    const f16* __restrict__ Ap, const f16* __restrict__ Bp,
    const float* __restrict__ bout, float* __restrict__ out) {
  __shared__ f16 Alds[4096];
  __shared__ f16 Blds[4096];
  const int KH = 128;

  int tid = threadIdx.x;
  int w = tid >> 6, lane = tid & 63, quad = lane >> 4, lc = lane & 15;
  int mh = w & 1, nh = w >> 1;
  size_t rb0 = (size_t)blockIdx.y * 2;
  size_t nb0 = (size_t)blockIdx.x * 2;

  f32x4 acc[4][4];
#pragma unroll
  for (int a = 0; a < 4; a++)
#pragma unroll
    for (int b = 0; b < 4; b++) acc[a][b] = (f32x4){0.f, 0.f, 0.f, 0.f};

  int wv = tid >> 6;
  for (int kk = 0; kk < 32; kk++) {
    __syncthreads();
    GLOAD16(Ap + ((rb0 + 0) * KH + kk * 4) * 512 + tid * 8, &Alds[0    + wv * 512]);
    GLOAD16(Ap + ((rb0 + 1) * KH + kk * 4) * 512 + tid * 8, &Alds[2048 + wv * 512]);
    GLOAD16(Bp + ((nb0 + 0) * KH + kk * 4) * 512 + tid * 8, &Blds[0    + wv * 512]);
    GLOAD16(Bp + ((nb0 + 1) * KH + kk * 4) * 512 + tid * 8, &Blds[2048 + wv * 512]);
    __syncthreads();

    f16x8 af[4], bf[4];
#pragma unroll
    for (int i = 0; i < 4; i++)
      af[i] = *(const f16x8*)&Alds[(((mh * 4 + quad) * 64) + i * 16 + lc) * 8];
#pragma unroll
    for (int i = 0; i < 4; i++)
      bf[i] = *(const f16x8*)&Blds[(((nh * 4 + quad) * 64) + i * 16 + lc) * 8];
#pragma unroll
    for (int mt = 0; mt < 4; mt++)
#pragma unroll
      for (int nt = 0; nt < 4; nt++)
        acc[mt][nt] = __builtin_amdgcn_mfma_f32_16x16x32_f16(af[mt], bf[nt],
                                                             acc[mt][nt], 0, 0, 0);
  }

#pragma unroll
  for (int nt = 0; nt < 4; nt++) {
    int col = blockIdx.x * 128 + nh * 64 + nt * 16 + lc;
    if (col >= PREW) continue;
    float bv = bout[col];
#pragma unroll
    for (int mt = 0; mt < 4; mt++) {
      int row0 = blockIdx.y * 128 + mh * 64 + mt * 16 + quad * 4;
#pragma unroll
      for (int r = 0; r < 4; r++) {
        int rg = row0 + r;
        int t = rg >> 6, m = rg & 63;
        out[((size_t)m * TSEQ + t) * PREW + col] = acc[mt][nt][r] + bv;
      }
    }
  }
}

// ---------------- persistent bidirectional LSTM layer (one time-chunk) ----------------
// grid = 32 blocks: d = blk>>4 (0 fwd, 1 bwd), wg = blk&15 owns hidden units [wg*32, wg*32+32)
// pre:  chunked [2][128 tl][64 m][2048] f16 (i|f|g|o blocks of 512), tl = t & 127
// WhhP: B-panels [64 nb][64 kh][64][8]  (nb 0..31 dir0, 32..63 dir1)
// hbuf: A-panels [t][128 kh][64 m][8]   (kh = d*64 + j/8)  -- doubles as next-GEMM input
// cbuf: [2][16][256][8] fp32 c-state carried across chunk launches
__global__ __launch_bounds__(256, 1) void k_lstm(
    const f16* __restrict__ pre, const f16* __restrict__ WhhP,
    f16* __restrict__ hbuf, int* bars, float* __restrict__ cbuf, int s0) {
  __shared__ f16 hlds[64 * 64 * 8];       // 64KB: h_prev fragment-major [kh][m][e]
  __shared__ float glds[4 * 32 * 64];     // 32KB: gates [g][j][m]

  int tid = threadIdx.x;
  int lane = tid & 63, quad = lane >> 4, lc = lane & 15;
  int blk = blockIdx.x;
  int d = blk >> 4, wg = blk & 15;
  int j0 = wg * 32;
  int g = tid >> 6;                        // wave = gate (i,f,g,o)
  int wv = tid >> 6;

  // Whh fragments: resident in VGPRs for the whole chunk (16 k-iters x 2 n-tiles)
  f16x8 wf[16][2];
#pragma unroll
  for (int ki = 0; ki < 16; ki++)
#pragma unroll
    for (int nt = 0; nt < 2; nt++) {
      int col = g * HID + j0 + nt * 16 + lc;
      size_t nb = (size_t)d * 32 + (col >> 6);
      int n_ = col & 63;
      wf[ki][nt] = *(const f16x8*)&WhhP[((nb * 64 + ki * 4 + quad) * 64 + n_) * 8];
    }

  int m_ep = tid >> 2, jg = tid & 3;       // epilogue ownership: (m, 8 j's) fixed forever
  float* cp = cbuf + ((size_t)(d * 16 + wg) * 256 + tid) * 8;
  float cst[8];
  if (s0 == 0) {
#pragma unroll
    for (int i = 0; i < 8; i++) cst[i] = 0.f;
  } else {
#pragma unroll
    for (int i = 0; i < 8; i++) cst[i] = cp[i];
  }
  int* bar = &bars[d];

  for (int s = s0; s < s0 + CHUNK; s++) {
    int t = d ? (TSEQ - 1 - s) : s;
    f32x4 acc[4][2];
#pragma unroll
    for (int a = 0; a < 4; a++)
#pragma unroll
      for (int b = 0; b < 2; b++) acc[a][b] = (f32x4){0.f, 0.f, 0.f, 0.f};

    if (s > 0) {
      int tp = d ? t + 1 : t - 1;
      if (tid == 0) {
        while (__hip_atomic_load(bar, __ATOMIC_ACQUIRE, __HIP_MEMORY_SCOPE_AGENT) < 16 * s)
          __builtin_amdgcn_s_sleep(1);
      }
      __syncthreads();
      __threadfence();                     // acquire-side: invalidate before reading fresh h
      const f16* src = hbuf + ((size_t)tp * 128 + d * 64) * 512;
#pragma unroll
      for (int it = 0; it < 16; it++)
        GLOAD16(src + it * 2048 + tid * 8, &hlds[it * 2048 + wv * 512]);
      __syncthreads();                     // drains vmcnt

#pragma unroll
      for (int ki = 0; ki < 16; ki++) {
        f16x8 af[4];
#pragma unroll
        for (int mt = 0; mt < 4; mt++)
          af[mt] = *(const f16x8*)&hlds[(((ki * 4 + quad) * 64) + mt * 16 + lc) * 8];
#pragma unroll
        for (int mt = 0; mt < 4; mt++)
#pragma unroll
          for (int nt = 0; nt < 2; nt++)
            acc[mt][nt] = __builtin_amdgcn_mfma_f32_16x16x32_f16(af[mt], wf[ki][nt],
                                                                 acc[mt][nt], 0, 0, 0);
      }
    }

    // gates -> LDS [g][j][m]  (rows are 4 consecutive m -> b128)
#pragma unroll
    for (int nt = 0; nt < 2; nt++)
#pragma unroll
      for (int mt = 0; mt < 4; mt++)
        *(f32x4*)&glds[((g * 32 + nt * 16 + lc) * 64) + mt * 16 + quad * 4] = acc[mt][nt];
    __syncthreads();

    // epilogue: add pre, activations, update c (regs), emit h (f16)
    const f16* pp = pre + (((size_t)d * 128 + (t & 127)) * 64 + m_ep) * 2048 + j0 + jg * 8;
    f16x8 pi = *(const f16x8*)(pp + 0 * HID);
    f16x8 pf = *(const f16x8*)(pp + 1 * HID);
    f16x8 pg = *(const f16x8*)(pp + 2 * HID);
    f16x8 po = *(const f16x8*)(pp + 3 * HID);
    f16x8 hv;
#pragma unroll
    for (int e = 0; e < 8; e++) {
      int j = jg * 8 + e;
      float gi = glds[(0 * 32 + j) * 64 + m_ep] + (float)pi[e];
      float gf = glds[(1 * 32 + j) * 64 + m_ep] + (float)pf[e];
      float gg = glds[(2 * 32 + j) * 64 + m_ep] + (float)pg[e];
      float go = glds[(3 * 32 + j) * 64 + m_ep] + (float)po[e];
      float c = sigm(gf) * cst[e] + sigm(gi) * tanh_f(gg);
      cst[e] = c;
      hv[e] = (f16)(sigm(go) * tanh_f(c));
    }
    *(f16x8*)&hbuf[(((size_t)t * 128 + d * 64 + wg * 4 + jg) * 64 + m_ep) * 8] = hv;

    __threadfence();                       // release-side: flush h before posting
    __syncthreads();
    if (tid == 0)
      __hip_atomic_fetch_add(bar, 1, __ATOMIC_RELEASE, __HIP_MEMORY_SCOPE_AGENT);
  }

  // persist c-state for next chunk
#pragma unroll
  for (int i = 0; i < 8; i++) cp[i] = cst[i];
}

// ---------------- host ----------------
extern "C" void kernel_launch(void* const* d_in, const int* in_sizes, int n_in,
                              void* d_out, int out_size, void* d_ws, size_t ws_size,
                              hipStream_t stream) {
  (void)in_sizes; (void)n_in; (void)out_size;
  const float* x    = (const float*)d_in[0];
  const float* Wih0 = (const float*)d_in[1];
  const float* Whh0 = (const float*)d_in[2];
  const float* b0   = (const float*)d_in[3];
  const float* Wih1 = (const float*)d_in[4];
  const float* Whh1 = (const float*)d_in[5];
  const float* b1   = (const float*)d_in[6];
  const float* Wout = (const float*)d_in[7];
  const float* bout = (const float*)d_in[8];
  float* out = (float*)d_out;
  char* ws = (char*)d_ws;

  size_t off = 0;
  auto carve = [&](size_t bytes) {
    size_t o = off; off += (bytes + 255) & ~(size_t)255; return o;
  };
  size_t o_bars  = carve(64);
  size_t o_cbuf  = carve((size_t)2 * 16 * 256 * 8 * 4);  // 256 KB c-state
  size_t o_xf    = carve((size_t)512 * 24 * 512 * 2);    // 12.6 MB
  size_t o_w0p   = carve((size_t)64 * 24 * 512 * 2);     // 1.6 MB
  size_t o_whh0p = carve((size_t)64 * 64 * 512 * 2);     // 4.2 MB
  size_t o_w1p   = carve((size_t)64 * 128 * 512 * 2);    // 8.4 MB
  size_t o_whh1p = carve((size_t)64 * 64 * 512 * 2);     // 4.2 MB
  size_t o_woutp = carve((size_t)4 * 128 * 512 * 2);     // 0.5 MB
  size_t o_h1    = carve((size_t)512 * 128 * 512 * 2);   // 67 MB
  size_t o_h2    = carve((size_t)512 * 128 * 512 * 2);   // 67 MB
  size_t o_pre   = carve((size_t)2 * 128 * 64 * 2048 * 2); // 67 MB chunked
  // total ~234 MB

  if (ws_size < off) {  // diagnostic: absmax will report ws size in MB
    k_sent<<<1, 1, 0, stream>>>(out, (float)(ws_size >> 20));
    return;
  }

  int*   bars  = (int*)(ws + o_bars);
  float* cbuf  = (float*)(ws + o_cbuf);
  f16*   xf    = (f16*)(ws + o_xf);
  f16*   w0p   = (f16*)(ws + o_w0p);
  f16*   whh0p = (f16*)(ws + o_whh0p);
  f16*   w1p   = (f16*)(ws + o_w1p);
  f16*   whh1p = (f16*)(ws + o_whh1p);
  f16*   woutp = (f16*)(ws + o_woutp);
  f16*   h1    = (f16*)(ws + o_h1);
  f16*   h2    = (f16*)(ws + o_h2);
  f16*   pre   = (f16*)(ws + o_pre);

  k_zero_bars<<<1, 64, 0, stream>>>(bars);
  k_conv_x<<<3072, 256, 0, stream>>>(x, xf);
  k_conv_w<<<384,  256, 0, stream>>>(Wih0, w0p,   4096, 168,  24,  98304);
  k_conv_w<<<1024, 256, 0, stream>>>(Whh0, whh0p, 4096, 512,  64,  262144);
  k_conv_w<<<2048, 256, 0, stream>>>(Wih1, w1p,   4096, 1024, 128, 524288);
  k_conv_w<<<1024, 256, 0, stream>>>(Whh1, whh1p, 4096, 512,  64,  262144);
  k_conv_w<<<128,  256, 0, stream>>>(Wout, woutp, 168,  1024, 128, 32768);

  // layer 0: 4 time-chunks of (pre-GEMM chunk -> persistent lstm chunk)
  for (int c = 0; c < 4; c++) {
    int tb0 = 128 * c, tb1 = 384 - 128 * c;
    k_gemm_pre<<<dim3(16, 64, 2), 256, 0, stream>>>(xf, w0p, b0, pre, 24, tb0, tb1);
    k_lstm<<<32, 256, 0, stream>>>(pre, whh0p, h1, bars, cbuf, 128 * c);
  }
  // layer 1
  for (int c = 0; c < 4; c++) {
    int tb0 = 128 * c, tb1 = 384 - 128 * c;
    k_gemm_pre<<<dim3(16, 64, 2), 256, 0, stream>>>(h1, w1p, b1, pre, 128, tb0, tb1);
    k_lstm<<<32, 256, 0, stream>>>(pre, whh1p, h2, bars + 8, cbuf, 128 * c);
  }
  k_gemm_out<<<dim3(2, 256, 1), 256, 0, stream>>>(h2, woutp, bout, out);
}

// Round 4
// 7617.415 us; speedup vs baseline: 1.5262x; 1.5262x over previous
//
#include <hip/hip_runtime.h>

// ---------------- types / helpers ----------------
typedef _Float16 f16;
typedef _Float16 f16x8 __attribute__((ext_vector_type(8)));
typedef float    f32x4 __attribute__((ext_vector_type(4)));

#define GLOAD16(gptr, lptr)                                                    \
  __builtin_amdgcn_global_load_lds(                                            \
      (const __attribute__((address_space(1))) void*)(gptr),                   \
      (__attribute__((address_space(3))) void*)(lptr), 16, 0, 0)

static __device__ __forceinline__ float sigm(float x) {
  return 1.f / (1.f + __expf(-x));
}
static __device__ __forceinline__ float tanh_f(float x) {
  return 2.f / (1.f + __expf(-2.f * x)) - 1.f;   // graceful at +-inf
}

// problem constants
#define TSEQ 512
#define BATCH 64
#define HID 512
#define INW 168
#define PREW 168
#define CHUNK 128   // time steps per pre-GEMM / lstm chunk (TSEQ/CHUNK = 4)

// ---------------- tiny kernels ----------------
__global__ void k_zero_bars(int* bars) {
  if (threadIdx.x < 16) bars[threadIdx.x] = 0;
}

__global__ void k_sent(float* out, float v) { out[0] = v; }

// x [B][T][168] fp32 -> A-panels xf[t][kh<24][m<64][e<8] f16, K padded 168->192 with zeros
__global__ void k_conv_x(const float* __restrict__ x, f16* __restrict__ xf) {
  int cid = blockIdx.x * 256 + threadIdx.x;          // 512*24*64
  int m  = cid & 63;
  int kh = (cid >> 6) % 24;
  int t  = cid / (64 * 24);
  f16x8 o;
  if (kh < 21) {
    const float* p = x + ((size_t)m * TSEQ + t) * INW + kh * 8;
#pragma unroll
    for (int i = 0; i < 8; i++) o[i] = (f16)p[i];
  } else {
#pragma unroll
    for (int i = 0; i < 8; i++) o[i] = (f16)0.f;
  }
  *(f16x8*)(xf + (size_t)cid * 8) = o;
}

// W fp32 [Nrows][K] -> B-panels P[nb][kh<KHp][n'<64][e<8] f16, zero-padded in n and k
__global__ void k_conv_w(const float* __restrict__ W, f16* __restrict__ P,
                         int Nrows, int K, int KHp, int total) {
  int cid = blockIdx.x * 256 + threadIdx.x;
  if (cid >= total) return;
  int n_ = cid & 63;
  int kh = (cid >> 6) % KHp;
  int nb = cid / (64 * KHp);
  int row = nb * 64 + n_;
  f16x8 o;
#pragma unroll
  for (int i = 0; i < 8; i++) {
    int k = kh * 8 + i;
    float v = (row < Nrows && k < K) ? W[(size_t)row * K + k] : 0.f;
    o[i] = (f16)v;
  }
  *(f16x8*)(P + (size_t)cid * 8) = o;
}

// ---------------- GEMM: pre[d][tl<128][m<64][2048] f16 = Apanels @ Bpanels^T + bias --------
__global__ __launch_bounds__(256) void k_gemm_pre(
    const f16* __restrict__ Ap, const f16* __restrict__ Bp,
    const float* __restrict__ bias, f16* __restrict__ Cpre, int KH,
    int tb0, int tb1) {
  __shared__ f16 Alds[4096];
  __shared__ f16 Blds[4096];
  __shared__ f16 Clds[128 * 128];

  int tid = threadIdx.x;
  int w = tid >> 6, lane = tid & 63, quad = lane >> 4, lc = lane & 15;
  int mh = w & 1, nh = w >> 1;
  int d = blockIdx.z;
  int tBase = d ? tb1 : tb0;
  size_t rbA0 = (size_t)tBase + blockIdx.y * 2;      // global t of first row-block
  size_t nb0 = (size_t)d * 32 + blockIdx.x * 2;
  int kIters = KH >> 2;

  f32x4 acc[4][4];
#pragma unroll
  for (int a = 0; a < 4; a++)
#pragma unroll
    for (int b = 0; b < 4; b++) acc[a][b] = (f32x4){0.f, 0.f, 0.f, 0.f};

  int wv = tid >> 6;
  for (int kk = 0; kk < kIters; kk++) {
    __syncthreads();
    GLOAD16(Ap + ((rbA0 + 0) * KH + kk * 4) * 512 + tid * 8, &Alds[0    + wv * 512]);
    GLOAD16(Ap + ((rbA0 + 1) * KH + kk * 4) * 512 + tid * 8, &Alds[2048 + wv * 512]);
    GLOAD16(Bp + ((nb0 + 0) * KH + kk * 4) * 512 + tid * 8, &Blds[0    + wv * 512]);
    GLOAD16(Bp + ((nb0 + 1) * KH + kk * 4) * 512 + tid * 8, &Blds[2048 + wv * 512]);
    __syncthreads();

    f16x8 af[4], bf[4];
#pragma unroll
    for (int i = 0; i < 4; i++)
      af[i] = *(const f16x8*)&Alds[(((mh * 4 + quad) * 64) + i * 16 + lc) * 8];
#pragma unroll
    for (int i = 0; i < 4; i++)
      bf[i] = *(const f16x8*)&Blds[(((nh * 4 + quad) * 64) + i * 16 + lc) * 8];
#pragma unroll
    for (int mt = 0; mt < 4; mt++)
#pragma unroll
      for (int nt = 0; nt < 4; nt++)
        acc[mt][nt] = __builtin_amdgcn_mfma_f32_16x16x32_f16(af[mt], bf[nt],
                                                             acc[mt][nt], 0, 0, 0);
  }
  __syncthreads();

  // bias + f16 convert into Clds [row][col]
#pragma unroll
  for (int nt = 0; nt < 4; nt++) {
    int col = nh * 64 + nt * 16 + lc;
    float bv = bias[d * 2048 + blockIdx.x * 128 + col];
#pragma unroll
    for (int mt = 0; mt < 4; mt++) {
      int row0 = mh * 64 + mt * 16 + quad * 4;
#pragma unroll
      for (int r = 0; r < 4; r++)
        Clds[(row0 + r) * 128 + col] = (f16)(acc[mt][nt][r] + bv);
    }
  }
  __syncthreads();

  // coalesced write-out into chunked pre[d][tl][m][2048]
  int row = tid >> 1, half = tid & 1;
  size_t rg = (size_t)blockIdx.y * 128 + row;        // tl*64 + m
  f16* dst = Cpre + ((size_t)d * 8192 + rg) * 2048 + blockIdx.x * 128 + half * 64;
  const f16* srcl = &Clds[row * 128 + half * 64];
#pragma unroll
  for (int i = 0; i < 8; i++) *(f16x8*)(dst + i * 8) = *(const f16x8*)(srcl + i * 8);
}

// ---------------- GEMM out: out[m][t][168] fp32 = h2panels @ Woutpanels^T + bout ----------------
__global__ __launch_bounds__(256) void k_gemm_out(
    const f16* __restrict__ Ap, const f16* __restrict__ Bp,
    const float* __restrict__ bout, float* __restrict__ out) {
  __shared__ f16 Alds[4096];
  __shared__ f16 Blds[4096];
  const int KH = 128;

  int tid = threadIdx.x;
  int w = tid >> 6, lane = tid & 63, quad = lane >> 4, lc = lane & 15;
  int mh = w & 1, nh = w >> 1;
  size_t rb0 = (size_t)blockIdx.y * 2;
  size_t nb0 = (size_t)blockIdx.x * 2;

  f32x4 acc[4][4];
#pragma unroll
  for (int a = 0; a < 4; a++)
#pragma unroll
    for (int b = 0; b < 4; b++) acc[a][b] = (f32x4){0.f, 0.f, 0.f, 0.f};

  int wv = tid >> 6;
  for (int kk = 0; kk < 32; kk++) {
    __syncthreads();
    GLOAD16(Ap + ((rb0 + 0) * KH + kk * 4) * 512 + tid * 8, &Alds[0    + wv * 512]);
    GLOAD16(Ap + ((rb0 + 1) * KH + kk * 4) * 512 + tid * 8, &Alds[2048 + wv * 512]);
    GLOAD16(Bp + ((nb0 + 0) * KH + kk * 4) * 512 + tid * 8, &Blds[0    + wv * 512]);
    GLOAD16(Bp + ((nb0 + 1) * KH + kk * 4) * 512 + tid * 8, &Blds[2048 + wv * 512]);
    __syncthreads();

    f16x8 af[4], bf[4];
#pragma unroll
    for (int i = 0; i < 4; i++)
      af[i] = *(const f16x8*)&Alds[(((mh * 4 + quad) * 64) + i * 16 + lc) * 8];
#pragma unroll
    for (int i = 0; i < 4; i++)
      bf[i] = *(const f16x8*)&Blds[(((nh * 4 + quad) * 64) + i * 16 + lc) * 8];
#pragma unroll
    for (int mt = 0; mt < 4; mt++)
#pragma unroll
      for (int nt = 0; nt < 4; nt++)
        acc[mt][nt] = __builtin_amdgcn_mfma_f32_16x16x32_f16(af[mt], bf[nt],
                                                             acc[mt][nt], 0, 0, 0);
  }

#pragma unroll
  for (int nt = 0; nt < 4; nt++) {
    int col = blockIdx.x * 128 + nh * 64 + nt * 16 + lc;
    if (col >= PREW) continue;
    float bv = bout[col];
#pragma unroll
    for (int mt = 0; mt < 4; mt++) {
      int row0 = blockIdx.y * 128 + mh * 64 + mt * 16 + quad * 4;
#pragma unroll
      for (int r = 0; r < 4; r++) {
        int rg = row0 + r;
        int t = rg >> 6, m = rg & 63;
        out[((size_t)m * TSEQ + t) * PREW + col] = acc[mt][nt][r] + bv;
      }
    }
  }
}

// ---------------- persistent bidirectional LSTM layer (one time-chunk) ----------------
// Sync protocol (r4): NO __threadfence (agent fences = buffer_wbl2/buffer_inv = whole-L2
// maintenance, ~10us/step observed). Instead h-exchange uses sc0 sc1 (L2-bypass, L3
// coherence point) loads/stores via inline asm; ordering = s_waitcnt vmcnt(0) before a
// RELAXED agent-scope atomic post; readers poll with RELAXED loads (no buffer_inv).
__global__ __launch_bounds__(256, 1) void k_lstm(
    const f16* __restrict__ pre, const f16* __restrict__ WhhP,
    f16* __restrict__ hbuf, int* bars, float* __restrict__ cbuf, int s0) {
  __shared__ f16 hlds[64 * 64 * 8];       // 64KB: h_prev fragment-major [kh][m][e]
  __shared__ float glds[4 * 32 * 64];     // 32KB: gates [g][j][m]

  int tid = threadIdx.x;
  int lane = tid & 63, quad = lane >> 4, lc = lane & 15;
  int blk = blockIdx.x;
  int d = blk >> 4, wg = blk & 15;
  int j0 = wg * 32;
  int g = tid >> 6;                        // wave = gate (i,f,g,o)

  // Whh fragments: resident in VGPRs/AGPRs for the whole chunk (16 k-iters x 2 n-tiles)
  f16x8 wf[16][2];
#pragma unroll
  for (int ki = 0; ki < 16; ki++)
#pragma unroll
    for (int nt = 0; nt < 2; nt++) {
      int col = g * HID + j0 + nt * 16 + lc;
      size_t nb = (size_t)d * 32 + (col >> 6);
      int n_ = col & 63;
      wf[ki][nt] = *(const f16x8*)&WhhP[((nb * 64 + ki * 4 + quad) * 64 + n_) * 8];
    }

  int m_ep = tid >> 2, jg = tid & 3;       // epilogue ownership: (m, 8 j's) fixed forever
  float* cp = cbuf + ((size_t)(d * 16 + wg) * 256 + tid) * 8;
  float cst[8];
  if (s0 == 0) {
#pragma unroll
    for (int i = 0; i < 8; i++) cst[i] = 0.f;
  } else {
#pragma unroll
    for (int i = 0; i < 8; i++) cst[i] = cp[i];
  }
  int* bar = &bars[d];

  for (int s = s0; s < s0 + CHUNK; s++) {
    int t = d ? (TSEQ - 1 - s) : s;

    // pre-activation loads hoisted: independent of h, latency hides under spin+h-load
    const f16* pp = pre + (((size_t)d * 128 + (t & 127)) * 64 + m_ep) * 2048 + j0 + jg * 8;
    f16x8 pi = *(const f16x8*)(pp + 0 * HID);
    f16x8 pf = *(const f16x8*)(pp + 1 * HID);
    f16x8 pg = *(const f16x8*)(pp + 2 * HID);
    f16x8 po = *(const f16x8*)(pp + 3 * HID);

    f32x4 acc[4][2];
#pragma unroll
    for (int a = 0; a < 4; a++)
#pragma unroll
      for (int b = 0; b < 2; b++) acc[a][b] = (f32x4){0.f, 0.f, 0.f, 0.f};

    if (s > 0) {
      int tp = d ? t + 1 : t - 1;
      if (tid == 0) {
        while (__hip_atomic_load(bar, __ATOMIC_RELAXED, __HIP_MEMORY_SCOPE_AGENT) < 16 * s)
          __builtin_amdgcn_s_sleep(1);
      }
      __syncthreads();                     // all loads below are execution-ordered after poll

      // h_prev: L2-bypass loads from L3 coherence point, then stage to LDS
      const f16* src = hbuf + ((size_t)tp * 128 + d * 64) * 512 + tid * 8;
      f32x4 tmp[16];
#pragma unroll
      for (int it = 0; it < 16; it++) {
        const f16* p = src + it * 2048;
        asm volatile("global_load_dwordx4 %0, %1, off sc0 sc1"
                     : "=v"(tmp[it]) : "v"(p) : "memory");
      }
      asm volatile("s_waitcnt vmcnt(0)" ::: "memory");
#pragma unroll
      for (int it = 0; it < 16; it++)
        *(f32x4*)&hlds[it * 2048 + tid * 8] = tmp[it];
      __syncthreads();

#pragma unroll
      for (int ki = 0; ki < 16; ki++) {
        f16x8 af[4];
#pragma unroll
        for (int mt = 0; mt < 4; mt++)
          af[mt] = *(const f16x8*)&hlds[(((ki * 4 + quad) * 64) + mt * 16 + lc) * 8];
#pragma unroll
        for (int mt = 0; mt < 4; mt++)
#pragma unroll
          for (int nt = 0; nt < 2; nt++)
            acc[mt][nt] = __builtin_amdgcn_mfma_f32_16x16x32_f16(af[mt], wf[ki][nt],
                                                                 acc[mt][nt], 0, 0, 0);
      }
    }

    // gates -> LDS [g][j][m]  (rows are 4 consecutive m -> b128)
#pragma unroll
    for (int nt = 0; nt < 2; nt++)
#pragma unroll
      for (int mt = 0; mt < 4; mt++)
        *(f32x4*)&glds[((g * 32 + nt * 16 + lc) * 64) + mt * 16 + quad * 4] = acc[mt][nt];
    __syncthreads();

    // epilogue: add pre, activations, update c (regs), emit h (f16)
    f16x8 hv;
#pragma unroll
    for (int e = 0; e < 8; e++) {
      int j = jg * 8 + e;
      float gi = glds[(0 * 32 + j) * 64 + m_ep] + (float)pi[e];
      float gf = glds[(1 * 32 + j) * 64 + m_ep] + (float)pf[e];
      float gg = glds[(2 * 32 + j) * 64 + m_ep] + (float)pg[e];
      float go = glds[(3 * 32 + j) * 64 + m_ep] + (float)po[e];
      float c = sigm(gf) * cst[e] + sigm(gi) * tanh_f(gg);
      cst[e] = c;
      hv[e] = (f16)(sigm(go) * tanh_f(c));
    }
    f16* hdst = &hbuf[(((size_t)t * 128 + d * 64 + wg * 4 + jg) * 64 + m_ep) * 8];
    f32x4 hv4 = *(f32x4*)&hv;
    asm volatile("global_store_dwordx4 %0, %1, off sc0 sc1"
                 :: "v"(hdst), "v"(hv4) : "memory");
    asm volatile("s_waitcnt vmcnt(0)" ::: "memory");   // h visible at L3 before post
    __syncthreads();                                   // all 256 threads' stores done
    if (tid == 0)
      __hip_atomic_fetch_add(bar, 1, __ATOMIC_RELAXED, __HIP_MEMORY_SCOPE_AGENT);
  }

  // persist c-state for next chunk
#pragma unroll
  for (int i = 0; i < 8; i++) cp[i] = cst[i];

  // sync block epilogue: make sure normal-path c writes land before kernel end (implicit)
}

// ---------------- host ----------------
extern "C" void kernel_launch(void* const* d_in, const int* in_sizes, int n_in,
                              void* d_out, int out_size, void* d_ws, size_t ws_size,
                              hipStream_t stream) {
  (void)in_sizes; (void)n_in; (void)out_size;
  const float* x    = (const float*)d_in[0];
  const float* Wih0 = (const float*)d_in[1];
  const float* Whh0 = (const float*)d_in[2];
  const float* b0   = (const float*)d_in[3];
  const float* Wih1 = (const float*)d_in[4];
  const float* Whh1 = (const float*)d_in[5];
  const float* b1   = (const float*)d_in[6];
  const float* Wout = (const float*)d_in[7];
  const float* bout = (const float*)d_in[8];
  float* out = (float*)d_out;
  char* ws = (char*)d_ws;

  size_t off = 0;
  auto carve = [&](size_t bytes) {
    size_t o = off; off += (bytes + 255) & ~(size_t)255; return o;
  };
  size_t o_bars  = carve(64);
  size_t o_cbuf  = carve((size_t)2 * 16 * 256 * 8 * 4);  // 256 KB c-state
  size_t o_xf    = carve((size_t)512 * 24 * 512 * 2);    // 12.6 MB
  size_t o_w0p   = carve((size_t)64 * 24 * 512 * 2);     // 1.6 MB
  size_t o_whh0p = carve((size_t)64 * 64 * 512 * 2);     // 4.2 MB
  size_t o_w1p   = carve((size_t)64 * 128 * 512 * 2);    // 8.4 MB
  size_t o_whh1p = carve((size_t)64 * 64 * 512 * 2);     // 4.2 MB
  size_t o_woutp = carve((size_t)4 * 128 * 512 * 2);     // 0.5 MB
  size_t o_h1    = carve((size_t)512 * 128 * 512 * 2);   // 67 MB
  size_t o_h2    = carve((size_t)512 * 128 * 512 * 2);   // 67 MB
  size_t o_pre   = carve((size_t)2 * 128 * 64 * 2048 * 2); // 67 MB chunked
  // total ~234 MB

  if (ws_size < off) {  // diagnostic: absmax will report ws size in MB
    k_sent<<<1, 1, 0, stream>>>(out, (float)(ws_size >> 20));
    return;
  }

  int*   bars  = (int*)(ws + o_bars);
  float* cbuf  = (float*)(ws + o_cbuf);
  f16*   xf    = (f16*)(ws + o_xf);
  f16*   w0p   = (f16*)(ws + o_w0p);
  f16*   whh0p = (f16*)(ws + o_whh0p);
  f16*   w1p   = (f16*)(ws + o_w1p);
  f16*   whh1p = (f16*)(ws + o_whh1p);
  f16*   woutp = (f16*)(ws + o_woutp);
  f16*   h1    = (f16*)(ws + o_h1);
  f16*   h2    = (f16*)(ws + o_h2);
  f16*   pre   = (f16*)(ws + o_pre);

  k_zero_bars<<<1, 64, 0, stream>>>(bars);
  k_conv_x<<<3072, 256, 0, stream>>>(x, xf);
  k_conv_w<<<384,  256, 0, stream>>>(Wih0, w0p,   4096, 168,  24,  98304);
  k_conv_w<<<1024, 256, 0, stream>>>(Whh0, whh0p, 4096, 512,  64,  262144);
  k_conv_w<<<2048, 256, 0, stream>>>(Wih1, w1p,   4096, 1024, 128, 524288);
  k_conv_w<<<1024, 256, 0, stream>>>(Whh1, whh1p, 4096, 512,  64,  262144);
  k_conv_w<<<128,  256, 0, stream>>>(Wout, woutp, 168,  1024, 128, 32768);

  // layer 0: 4 time-chunks of (pre-GEMM chunk -> persistent lstm chunk)
  for (int c = 0; c < 4; c++) {
    int tb0 = 128 * c, tb1 = 384 - 128 * c;
    k_gemm_pre<<<dim3(16, 64, 2), 256, 0, stream>>>(xf, w0p, b0, pre, 24, tb0, tb1);
    k_lstm<<<32, 256, 0, stream>>>(pre, whh0p, h1, bars, cbuf, 128 * c);
  }
  // layer 1
  for (int c = 0; c < 4; c++) {
    int tb0 = 128 * c, tb1 = 384 - 128 * c;
    k_gemm_pre<<<dim3(16, 64, 2), 256, 0, stream>>>(h1, w1p, b1, pre, 128, tb0, tb1);
    k_lstm<<<32, 256, 0, stream>>>(pre, whh1p, h2, bars + 8, cbuf, 128 * c);
  }
  k_gemm_out<<<dim3(2, 256, 1), 256, 0, stream>>>(h2, woutp, bout, out);
}